// Round 11
// baseline (538.086 us; speedup 1.0000x reference)
//
#include <hip/hip_runtime.h>
#include <math.h>

#define TOK 2048
#define NDIM 1024

typedef __attribute__((ext_vector_type(4))) float f32x4;
typedef __attribute__((ext_vector_type(8))) short s16x8;
typedef __attribute__((ext_vector_type(4))) short s16x4;

__device__ __forceinline__ short f2bf(float x) {
  unsigned int u = __builtin_bit_cast(unsigned int, x);
  unsigned int r = (u + 0x7fffu + ((u >> 16) & 1u)) >> 16;
  return (short)r;
}
__device__ __forceinline__ void gload_lds16(const void* g, void* l) {
  __builtin_amdgcn_global_load_lds((const __attribute__((address_space(1))) void*)g,
                                   (__attribute__((address_space(3))) void*)l, 16, 0, 0);
}

// ------- Weight pack: [K][N] fp32 -> tiles [nt][kt], each 128n x 64k bf16 (16KB) -------
// Chunk at byte (col*128 + od*16) holds W[k0+o*8+j][n0+col], o = od ^ (col&7).
struct PackP { const float* src; short* dst; int K, N, nkt; };
__global__ __launch_bounds__(256)
void pack_k(PackP p)
{
  __shared__ short T[64][264];
  const int nkt = p.nkt;
  const int cb = blockIdx.x / nkt, kt = blockIdx.x % nkt;
  const int ntn = p.N >> 7;
  const float* src = p.src + (size_t)blockIdx.y * p.K * p.N + (size_t)(kt * 64) * p.N + cb * 256;
  const int t = threadIdx.x;
  #pragma unroll
  for (int i = 0; i < 16; ++i) {
    const int r = i * 4 + (t >> 6);
    const f32x4 v = *(const f32x4*)(src + (size_t)r * p.N + (t & 63) * 4);
    short* d = &T[r][(t & 63) * 4];
    d[0] = f2bf(v[0]); d[1] = f2bf(v[1]); d[2] = f2bf(v[2]); d[3] = f2bf(v[3]);
  }
  __syncthreads();
  #pragma unroll
  for (int j = 0; j < 2; ++j) {  // two 128-wide tiles per 256-col block
    short* dst = p.dst + ((size_t)(blockIdx.y * ntn + cb * 2 + j) * nkt + kt) * 8192;
    #pragma unroll
    for (int jj = 0; jj < 4; ++jj) {
      const int ch = t * 4 + jj;
      const int col = ch >> 3, od = ch & 7, o = od ^ (col & 7);
      s16x8 v;
      #pragma unroll
      for (int kk = 0; kk < 8; ++kk) v[kk] = T[o * 8 + kk][j * 128 + col];
      *(s16x8*)(dst + ch * 8) = v;
    }
  }
}

// ---------------- LayerNorm: fp32 in -> bf16 out ----------------
__global__ __launch_bounds__(256)
void ln_k(const float* __restrict__ x, const float* __restrict__ g,
          const float* __restrict__ bb, short* __restrict__ out)
{
  const int row = blockIdx.x, tid = threadIdx.x;
  const f32x4 xv = *(const f32x4*)(x + (size_t)row * NDIM + tid * 4);
  float s = xv[0] + xv[1] + xv[2] + xv[3];
  float s2 = xv[0]*xv[0] + xv[1]*xv[1] + xv[2]*xv[2] + xv[3]*xv[3];
  #pragma unroll
  for (int m = 1; m < 64; m <<= 1) { s += __shfl_xor(s, m); s2 += __shfl_xor(s2, m); }
  __shared__ float red[8];
  const int w = tid >> 6, l = tid & 63;
  if (l == 0) { red[w] = s; red[4 + w] = s2; }
  __syncthreads();
  s = red[0] + red[1] + red[2] + red[3];
  s2 = red[4] + red[5] + red[6] + red[7];
  const float mean = s * (1.0f / NDIM);
  const float var = s2 * (1.0f / NDIM) - mean * mean;
  const float rstd = rsqrtf(var + 1e-5f);
  const f32x4 gv = *(const f32x4*)(g + tid * 4);
  const f32x4 bv = *(const f32x4*)(bb + tid * 4);
  s16x4 ov;
  #pragma unroll
  for (int j = 0; j < 4; ++j) ov[j] = f2bf((xv[j] - mean) * rstd * gv[j] + bv[j]);
  *(s16x4*)(out + (size_t)row * NDIM + tid * 4) = ov;
}

// ---------------- Gate: fp32 LN recompute + gate/coef softmax + buckets ----------------
__global__ __launch_bounds__(256)
void gate_k(const float* __restrict__ x1, const float* __restrict__ g,
            const float* __restrict__ bb, const float* __restrict__ gw,
            const float* __restrict__ cw, const float* __restrict__ cb,
            int* __restrict__ counts, int* __restrict__ bucket,
            float* __restrict__ gs, float* __restrict__ c1o)
{
  const int tid = threadIdx.x, l = tid & 63, w = tid >> 6;
  const int t = blockIdx.x * 4 + w;
  f32x4 xv[4];
  #pragma unroll
  for (int it = 0; it < 4; ++it)
    xv[it] = *(const f32x4*)(x1 + (size_t)t * NDIM + it * 256 + l * 4);
  float s = 0.f, s2 = 0.f;
  #pragma unroll
  for (int it = 0; it < 4; ++it)
    #pragma unroll
    for (int j = 0; j < 4; ++j) { s += xv[it][j]; s2 += xv[it][j] * xv[it][j]; }
  #pragma unroll
  for (int m = 1; m < 64; m <<= 1) { s += __shfl_xor(s, m); s2 += __shfl_xor(s2, m); }
  const float mean = s * (1.0f / NDIM);
  const float rstd = rsqrtf(s2 * (1.0f / NDIM) - mean * mean + 1e-5f);
  float acc[10];
  #pragma unroll
  for (int j = 0; j < 10; ++j) acc[j] = 0.f;
  #pragma unroll
  for (int it = 0; it < 4; ++it) {
    #pragma unroll
    for (int j = 0; j < 4; ++j) {
      const int d0 = it * 256 + l * 4 + j;
      const float xn = (xv[it][j] - mean) * rstd * g[d0] + bb[d0];
      const f32x4 g0 = *(const f32x4*)(gw + (size_t)d0 * 8);
      const f32x4 g1 = *(const f32x4*)(gw + (size_t)d0 * 8 + 4);
      #pragma unroll
      for (int q = 0; q < 4; ++q) { acc[q] += xn * g0[q]; acc[4 + q] += xn * g1[q]; }
      acc[8] += xn * cw[d0 * 2]; acc[9] += xn * cw[d0 * 2 + 1];
    }
  }
  #pragma unroll
  for (int j = 0; j < 10; ++j)
    #pragma unroll
    for (int m = 1; m < 64; m <<= 1) acc[j] += __shfl_xor(acc[j], m);
  if (l == 0) {
    int best = 0; float mx = acc[0];
    #pragma unroll
    for (int e = 1; e < 8; ++e) if (acc[e] > mx) { mx = acc[e]; best = e; }
    float se = 0.f;
    #pragma unroll
    for (int e = 0; e < 8; ++e) se += __expf(acc[e] - mx);
    const float gate_val = 1.0f / se;
    const float l0 = acc[8] + cb[0], l1 = acc[9] + cb[1];
    const float cmx = fmaxf(l0, l1);
    const float e0 = __expf(l0 - cmx), e1 = __expf(l1 - cmx);
    const float inv = 1.0f / (e0 + e1);
    const int pos = atomicAdd(&counts[best], 1);
    bucket[best * TOK + pos] = t;
    gs[t] = gate_val * e0 * inv;
    c1o[t] = e1 * inv;
  }
}

// ---------------- Sched: expert-sorted padded m-tile table ----------------
// table[0..22]: {expert, bucket_base, rows, 0}; table[23].x = tile count.
__global__ void sched_k(const int* __restrict__ counts, int4* __restrict__ table)
{
  if (threadIdx.x == 0) {
    int m = 0;
    for (int e = 0; e < 8; ++e) {
      const int c = counts[e];
      for (int t = 0; t * 128 < c; ++t) {
        const int rows = (c - t * 128 > 128) ? 128 : c - t * 128;
        table[m] = int4{e, e * TOK + t * 128, rows, 0};
        ++m;
      }
    }
    table[23] = int4{m, 0, 0, 0};
  }
}

// ---- bf16 MFMA GEMM, m97 structure: 128x128 tile, BK=64, single-buffer ----
// MODE 0: dense, store bf16 (QKV)            — column-chunk XCD swizzle
// MODE 1: dense split-K atomic resid (Wo)    — column-chunk XCD swizzle
// MODE 2: table-driven up-proj GELU bf16     — row-chunk XCD swizzle (CH=5, NMT=39)
// MODE 3: table-driven down-proj split-K     — row-chunk XCD swizzle
struct GemmP {
  const short* A; const short* A2; const short* Bp; const short* Bp2;
  const float* bias; const float* bias2;
  short* outh; short* outh2; float* outf;
  const float* resid; const float* gs; const float* c1;
  const int* bucket; const int4* table;
  int N, K, ktc, nmt;
};

template<int MODE>
__global__ __launch_bounds__(256, 4)
void gemm_k(GemmP p)
{
  __shared__ short Al[8192];  // 16KB: [row128][octd8][16B] xor-swizzled
  __shared__ short Bl[8192];  // 16KB: [col128][octd8][16B] xor-swizzled (packed)
  const int tid = threadIdx.x;
  const int l = tid & 63, w = tid >> 6;
  const int wr = w >> 1, wc = w & 1;
  const int ntn = p.N >> 7, nkt = p.K >> 6;
  const int z = blockIdx.z;
  const bool first = (z == 0);
  const int K = p.K, N = p.N;

  int nt, mt = 0, e = 0, bbase = 0, rows = 128;
  if (MODE <= 1) {
    // column-chunk: XCD owns contiguous nt columns; mt inner
    const int nwg = p.nmt * ntn;
    const int logical = (blockIdx.x & 7) * (nwg >> 3) + (blockIdx.x >> 3);
    nt = logical / p.nmt;
    mt = logical % p.nmt;
  } else {
    // row-chunk: XCD owns 5 consecutive mtg rows; nt outer sweep
    const int x = blockIdx.x & 7;
    const int r = blockIdx.x >> 3;
    const int CH = 5;
    nt = r / CH;
    const int mtg = x * CH + r % CH;
    if (mtg >= 39) return;
    if (mtg < 23) {
      const int emt = p.table[23].x;
      if (mtg >= emt) return;
      const int4 te = p.table[mtg];
      e = te.x; bbase = te.y; rows = te.z;
    } else { e = 8; mt = mtg - 23; }
  }

  const short* Abase = (MODE == 3 && e == 8) ? p.A2 : p.A;
  const float* bias = (MODE >= 2) ? (e < 8 ? p.bias + (size_t)e * N : p.bias2) : p.bias;
  const short* btile = (MODE >= 2)
      ? (e < 8 ? p.Bp + ((size_t)(e * ntn + nt) * nkt) * 8192
               : p.Bp2 + ((size_t)nt * nkt) * 8192)
      : p.Bp + ((size_t)nt * nkt) * 8192;
  const bool gathered = (MODE >= 2) && (e < 8);

  // A staging: chunk c = i*256+tid; row = c>>3, src k-octet = (tid&7)^(row&7)
  const short* aptr[4];
  #pragma unroll
  for (int i = 0; i < 4; ++i) {
    const int rl = (i * 256 + tid) >> 3;
    int row;
    if (gathered) row = p.bucket[bbase + (rl < rows ? rl : 0)];
    else row = mt * 128 + rl;
    aptr[i] = Abase + (size_t)row * K + ((tid & 7) ^ (rl & 7)) * 8;
  }

  const int kt0 = z * p.ktc, kt1 = kt0 + p.ktc;

  f32x4 acc[4][4] = {};
  for (int kt = kt0; kt < kt1; ++kt) {
    const short* bsrc = btile + kt * 8192;
    #pragma unroll
    for (int j = 0; j < 4; ++j)
      gload_lds16(bsrc + (j * 256 + tid) * 8, (char*)Bl + (j * 256 + (tid & 192)) * 16);
    #pragma unroll
    for (int i = 0; i < 4; ++i)
      gload_lds16(aptr[i] + kt * 64, (char*)Al + (i * 256 + (tid & 192)) * 16);
    __syncthreads();
    #pragma unroll
    for (int ks = 0; ks < 2; ++ks) {
      const int octd0 = ks * 4 + (l >> 4);
      s16x8 af[4], bfr[4];
      #pragma unroll
      for (int mf = 0; mf < 4; ++mf) {
        const int r = wr * 64 + mf * 16 + (l & 15);
        af[mf] = *(const s16x8*)((char*)Al + r * 128 + (octd0 ^ (r & 7)) * 16);
      }
      #pragma unroll
      for (int nf = 0; nf < 4; ++nf) {
        const int c2 = wc * 64 + nf * 16 + (l & 15);
        bfr[nf] = *(const s16x8*)((char*)Bl + c2 * 128 + (octd0 ^ (c2 & 7)) * 16);
      }
      #pragma unroll
      for (int mf = 0; mf < 4; ++mf)
        #pragma unroll
        for (int nf = 0; nf < 4; ++nf)
          acc[mf][nf] = __builtin_amdgcn_mfma_f32_16x16x32_bf16(af[mf], bfr[nf], acc[mf][nf], 0, 0, 0);
    }
    __syncthreads();
  }

  short* oh = (MODE == 2) ? (e < 8 ? p.outh : p.outh2) : p.outh;
  #pragma unroll
  for (int mf = 0; mf < 4; ++mf) {
    #pragma unroll
    for (int i = 0; i < 4; ++i) {
      const int rloc = wr * 64 + mf * 16 + (l >> 4) * 4 + i;
      int grow; bool valid = true;
      if (gathered) {
        valid = rloc < rows;
        grow = p.bucket[bbase + (valid ? rloc : 0)];
      } else grow = mt * 128 + rloc;
      float srow = 1.f;
      if (MODE == 3) srow = (e < 8) ? (valid ? p.gs[grow] : 0.f) : p.c1[grow];
      #pragma unroll
      for (int nf = 0; nf < 4; ++nf) {
        const int col = nt * 128 + wc * 64 + nf * 16 + (l & 15);
        const size_t off = (size_t)grow * N + col;
        const float bc = first ? bias[col] : 0.f;
        if (MODE == 0) {
          oh[off] = f2bf(acc[mf][nf][i] + bc);
        } else if (MODE == 1) {
          atomicAdd(&p.outf[off], acc[mf][nf][i] + bc + (first ? p.resid[off] : 0.f));
        } else if (MODE == 2) {
          const float v = acc[mf][nf][i] + bc;
          const float gv = 0.5f * v * (1.0f + erff(v * 0.70710678f));
          if (valid) oh[off] = f2bf(gv);
        } else if (MODE == 3) {
          if (valid)
            atomicAdd(&p.outf[off], (acc[mf][nf][i] + bc) * srow +
                      ((e == 8 && first) ? p.resid[off] : 0.f));
        }
      }
    }
  }
}

// ---------------- Flash attention: 4 waves x 16 q-rows, KV tiles of 64 ----------------
__global__ __launch_bounds__(256, 2)
void attn_k(const short* __restrict__ qkv, short* __restrict__ ctx)
{
  __shared__ short Klds[64 * 64];
  __shared__ short Vlds[64 * 64];
  __shared__ short Plds[4 * 16 * 64];
  const int tid = threadIdx.x, l = tid & 63, w = tid >> 6;
  const int qt = blockIdx.x;
  const int bh = blockIdx.y;
  const int b = bh >> 4, h = bh & 15;
  const size_t tbase = (size_t)b * 1024;

  const int sq = qt * 64 + w * 16 + (l & 15);
  s16x8 qf[2];
  #pragma unroll
  for (int ks = 0; ks < 2; ++ks)
    qf[ks] = *(const s16x8*)(qkv + (tbase + sq) * 3072 + h * 64 + ks * 32 + (l >> 4) * 8);

  f32x4 o[4] = {};
  float mrow[4], lrow[4];
  #pragma unroll
  for (int i = 0; i < 4; ++i) { mrow[i] = -1e30f; lrow[i] = 0.f; }

  for (int kt = 0; kt < 16; ++kt) {
    #pragma unroll
    for (int i = 0; i < 2; ++i) {
      const int s = i * 256 + tid;
      const int r = s >> 3, c = s & 7, csrc = c ^ (r & 7);
      const short* gsrc = qkv + (tbase + kt * 64 + r) * 3072 + 1024 + h * 64 + csrc * 8;
      gload_lds16(gsrc, (char*)Klds + (i * 256 + (tid & 192)) * 16);
    }
    #pragma unroll
    for (int i = 0; i < 2; ++i) {
      const int kv0 = (i * 4 + w) * 8;
      s16x8 vv;
      #pragma unroll
      for (int j = 0; j < 8; ++j)
        vv[j] = qkv[(tbase + kt * 64 + kv0 + j) * 3072 + 2048 + h * 64 + l];
      *(s16x8*)((char*)Vlds + ((l * 128 + kv0 * 2) ^ ((l & 7) << 4))) = vv;
    }
    __syncthreads();

    f32x4 sv[4];
    #pragma unroll
    for (int nf = 0; nf < 4; ++nf) {
      f32x4 a = {0.f, 0.f, 0.f, 0.f};
      const int kv = nf * 16 + (l & 15);
      #pragma unroll
      for (int ks = 0; ks < 2; ++ks) {
        const s16x8 kb = *(const s16x8*)((char*)Klds +
            ((kv * 128 + (ks * 32 + (l >> 4) * 8) * 2) ^ ((kv & 7) << 4)));
        a = __builtin_amdgcn_mfma_f32_16x16x32_bf16(qf[ks], kb, a, 0, 0, 0);
      }
      sv[nf] = a * 0.125f;
    }
    float sc[4], ps[4];
    #pragma unroll
    for (int i = 0; i < 4; ++i) {
      float m = fmaxf(fmaxf(sv[0][i], sv[1][i]), fmaxf(sv[2][i], sv[3][i]));
      #pragma unroll
      for (int msk = 1; msk < 16; msk <<= 1) m = fmaxf(m, __shfl_xor(m, msk));
      const float mn = fmaxf(mrow[i], m);
      sc[i] = __expf(mrow[i] - mn);
      mrow[i] = mn;
      ps[i] = 0.f;
    }
    #pragma unroll
    for (int nf = 0; nf < 4; ++nf)
      #pragma unroll
      for (int i = 0; i < 4; ++i) {
        const float pp = __expf(sv[nf][i] - mrow[i]);
        sv[nf][i] = pp;
        ps[i] += pp;
      }
    #pragma unroll
    for (int i = 0; i < 4; ++i) {
      #pragma unroll
      for (int msk = 1; msk < 16; msk <<= 1) ps[i] += __shfl_xor(ps[i], msk);
      lrow[i] = lrow[i] * sc[i] + ps[i];
    }
    #pragma unroll
    for (int nf = 0; nf < 4; ++nf)
      #pragma unroll
      for (int i = 0; i < 4; ++i) o[nf][i] *= sc[i];

    char* pw = (char*)Plds + w * 2048;
    #pragma unroll
    for (int nf = 0; nf < 4; ++nf)
      #pragma unroll
      for (int i = 0; i < 4; ++i) {
        const int q = (l >> 4) * 4 + i;
        *(short*)(pw + ((q * 128 + (nf * 16 + (l & 15)) * 2) ^ ((q & 7) << 4))) = f2bf(sv[nf][i]);
      }
    __syncthreads();
    #pragma unroll
    for (int ks = 0; ks < 2; ++ks) {
      const s16x8 pa = *(const s16x8*)(pw +
          (((l & 15) * 128 + (ks * 32 + (l >> 4) * 8) * 2) ^ ((l & 7) << 4)));
      #pragma unroll
      for (int nf = 0; nf < 4; ++nf) {
        const int dh = nf * 16 + (l & 15);
        const s16x8 vb = *(const s16x8*)((char*)Vlds +
            ((dh * 128 + (ks * 32 + (l >> 4) * 8) * 2) ^ ((dh & 7) << 4)));
        o[nf] = __builtin_amdgcn_mfma_f32_16x16x32_bf16(pa, vb, o[nf], 0, 0, 0);
      }
    }
    __syncthreads();
  }
  #pragma unroll
  for (int i = 0; i < 4; ++i) {
    const float inv = 1.0f / lrow[i];
    const size_t t = tbase + qt * 64 + w * 16 + (l >> 4) * 4 + i;
    #pragma unroll
    for (int nf = 0; nf < 4; ++nf)
      ctx[t * 1024 + h * 64 + nf * 16 + (l & 15)] = f2bf(o[nf][i] * inv);
  }
}

extern "C" void kernel_launch(void* const* d_in, const int* in_sizes, int n_in,
                              void* d_out, int out_size, void* d_ws, size_t ws_size,
                              hipStream_t stream)
{
  const float* x    = (const float*)d_in[0];
  const float* ln1g = (const float*)d_in[1];
  const float* ln1b = (const float*)d_in[2];
  const float* Wqkv = (const float*)d_in[3];
  const float* bqkv = (const float*)d_in[4];
  const float* Wo   = (const float*)d_in[5];
  const float* bo   = (const float*)d_in[6];
  const float* ln2g = (const float*)d_in[7];
  const float* ln2b = (const float*)d_in[8];
  const float* gw   = (const float*)d_in[9];
  const float* W1   = (const float*)d_in[10];
  const float* b1   = (const float*)d_in[11];
  const float* W2   = (const float*)d_in[12];
  const float* b2   = (const float*)d_in[13];
  const float* rW1  = (const float*)d_in[14];
  const float* rb1  = (const float*)d_in[15];
  const float* rW2  = (const float*)d_in[16];
  const float* rb2  = (const float*)d_in[17];
  const float* cw   = (const float*)d_in[18];
  const float* cb   = (const float*)d_in[19];
  float* out = (float*)d_out;

  char* ws = (char*)d_ws;
  const size_t MB = 1024 * 1024;
  short* xn1    = (short*)(ws + 0);          // 4 MB
  short* qkv    = (short*)(ws + 4 * MB);     // 12 MB
  short* he     = (short*)(ws + 4 * MB);     // 16 MB (aliases qkv+ctx, dead by then)
  short* ctx    = (short*)(ws + 16 * MB);    // 4 MB
  float* x1     = (float*)(ws + 20 * MB);    // 8 MB
  short* xn2    = (short*)(ws + 28 * MB);    // 4 MB
  short* hr     = (short*)(ws + 32 * MB);    // 16 MB
  int*   counts = (int*)(ws + 56 * MB);
  int*   bucket = (int*)(ws + 56 * MB + 256);
  float* gs     = (float*)(ws + 56 * MB + 256 + 64 * 1024);
  float* c1     = (float*)(ws + 56 * MB + 256 + 64 * 1024 + 8192);
  int4*  table  = (int4*)(ws + 57 * MB);
  short* Wqkvp  = (short*)(ws + 64 * MB);    // 6 MB
  short* Wop    = (short*)(ws + 70 * MB);    // 2 MB
  short* W1p    = (short*)(ws + 72 * MB);    // 64 MB
  short* W2p    = (short*)(ws + 136 * MB);   // 64 MB
  short* rW1p   = (short*)(ws + 200 * MB);   // 8 MB
  short* rW2p   = (short*)(ws + 208 * MB);   // 8 MB

  hipMemsetAsync(counts, 0, 8 * sizeof(int), stream);
  hipMemsetAsync(x1, 0, TOK * NDIM * sizeof(float), stream);
  hipMemsetAsync(out, 0, TOK * NDIM * sizeof(float), stream);

  // --- weight packing (tiles are 128n x 64k) ---
  PackP pk;
  pk = PackP{Wqkv, Wqkvp, 1024, 3072, 16}; pack_k<<<dim3(12 * 16, 1), 256, 0, stream>>>(pk);
  pk = PackP{Wo,   Wop,   1024, 1024, 16}; pack_k<<<dim3(4 * 16, 1), 256, 0, stream>>>(pk);
  pk = PackP{W1,   W1p,   1024, 4096, 16}; pack_k<<<dim3(16 * 16, 8), 256, 0, stream>>>(pk);
  pk = PackP{W2,   W2p,   4096, 1024, 64}; pack_k<<<dim3(4 * 64, 8), 256, 0, stream>>>(pk);
  pk = PackP{rW1,  rW1p,  1024, 4096, 16}; pack_k<<<dim3(16 * 16, 1), 256, 0, stream>>>(pk);
  pk = PackP{rW2,  rW2p,  4096, 1024, 64}; pack_k<<<dim3(4 * 64, 1), 256, 0, stream>>>(pk);

  ln_k<<<TOK, 256, 0, stream>>>(x, ln1g, ln1b, xn1);

  // qkv = xn1 @ Wqkv + bqkv   (nwg = 16*24 = 384)
  GemmP p{};
  p.A = xn1; p.Bp = Wqkvp; p.bias = bqkv; p.outh = qkv;
  p.N = 3072; p.K = 1024; p.ktc = 16; p.nmt = 16;
  gemm_k<0><<<dim3(384), 256, 0, stream>>>(p);

  attn_k<<<dim3(16, 32), 256, 0, stream>>>(qkv, ctx);

  // x1 = x + ctx @ Wo + bo  (nwg = 128, split-K = 2)
  p = GemmP{};
  p.A = ctx; p.Bp = Wop; p.bias = bo; p.outf = x1; p.resid = x;
  p.N = 1024; p.K = 1024; p.ktc = 8; p.nmt = 16;
  gemm_k<1><<<dim3(128, 1, 2), 256, 0, stream>>>(p);

  ln_k<<<TOK, 256, 0, stream>>>(x1, ln2g, ln2b, xn2);
  gate_k<<<TOK / 4, 256, 0, stream>>>(x1, ln2g, ln2b, gw, cw, cb, counts, bucket, gs, c1);
  sched_k<<<1, 64, 0, stream>>>(counts, table);

  // fused up-proj, table-driven, row-chunked: grid = 8 XCD * 5 rows * 32 nt = 1280
  p = GemmP{};
  p.A = xn2; p.Bp = W1p; p.Bp2 = rW1p; p.bias = b1; p.bias2 = rb1;
  p.outh = he; p.outh2 = hr; p.N = 4096; p.K = 1024; p.ktc = 16;
  p.bucket = bucket; p.table = table;
  gemm_k<2><<<dim3(8 * 5 * 32), 256, 0, stream>>>(p);

  // fused down-proj, table-driven, split-K=4: grid = 8*5*8 x 4
  p = GemmP{};
  p.A = he; p.A2 = hr; p.Bp = W2p; p.Bp2 = rW2p; p.bias = b2; p.bias2 = rb2;
  p.outf = out; p.resid = x1; p.gs = gs; p.c1 = c1;
  p.N = 1024; p.K = 4096; p.ktc = 16;
  p.bucket = bucket; p.table = table;
  gemm_k<3><<<dim3(8 * 5 * 8, 1, 4), 256, 0, stream>>>(p);
}

// Round 12
// 435.312 us; speedup vs baseline: 1.2361x; 1.2361x over previous
//
#include <hip/hip_runtime.h>
#include <math.h>

#define TOK 2048
#define NDIM 1024

typedef __attribute__((ext_vector_type(4))) float f32x4;
typedef __attribute__((ext_vector_type(8))) short s16x8;
typedef __attribute__((ext_vector_type(4))) short s16x4;

__device__ __forceinline__ short f2bf(float x) {
  unsigned int u = __builtin_bit_cast(unsigned int, x);
  unsigned int r = (u + 0x7fffu + ((u >> 16) & 1u)) >> 16;
  return (short)r;
}
__device__ __forceinline__ void gload_lds16(const void* g, void* l) {
  __builtin_amdgcn_global_load_lds((const __attribute__((address_space(1))) void*)g,
                                   (__attribute__((address_space(3))) void*)l, 16, 0, 0);
}

// ------- Weight pack body: [K][N] fp32 -> tiles [nt][kt], 128n x 64k bf16 (16KB) -------
// Chunk at byte (col*128 + od*16) holds W[k0+o*8+j][n0+col], o = od ^ (col&7).
struct PackP { const float* src; short* dst; int K, N, nkt; };

__device__ __forceinline__ void pack_body(const PackP& p, int bx, int by, int tid, char* smem)
{
  short (*T)[264] = (short(*)[264])smem;
  const int nkt = p.nkt;
  const int cb = bx / nkt, kt = bx % nkt;
  const int ntn = p.N >> 7;
  const float* src = p.src + (size_t)by * p.K * p.N + (size_t)(kt * 64) * p.N + cb * 256;
  #pragma unroll
  for (int i = 0; i < 16; ++i) {
    const int r = i * 4 + (tid >> 6);
    const f32x4 v = *(const f32x4*)(src + (size_t)r * p.N + (tid & 63) * 4);
    short* d = &T[r][(tid & 63) * 4];
    d[0] = f2bf(v[0]); d[1] = f2bf(v[1]); d[2] = f2bf(v[2]); d[3] = f2bf(v[3]);
  }
  __syncthreads();
  #pragma unroll
  for (int j = 0; j < 2; ++j) {
    short* dst = p.dst + ((size_t)(by * ntn + cb * 2 + j) * nkt + kt) * 8192;
    #pragma unroll
    for (int jj = 0; jj < 4; ++jj) {
      const int ch = tid * 4 + jj;
      const int col = ch >> 3, od = ch & 7, o = od ^ (col & 7);
      s16x8 v;
      #pragma unroll
      for (int kk = 0; kk < 8; ++kk) v[kk] = T[o * 8 + kk][j * 128 + col];
      *(s16x8*)(dst + ch * 8) = v;
    }
  }
}

__global__ __launch_bounds__(256)
void pack_k(PackP p)
{
  __shared__ char smem[34816];
  pack_body(p, blockIdx.x, blockIdx.y, threadIdx.x, smem);
}

// ---------------- LayerNorm: fp32 in -> bf16 out ----------------
__global__ __launch_bounds__(256)
void ln_k(const float* __restrict__ x, const float* __restrict__ g,
          const float* __restrict__ bb, short* __restrict__ out)
{
  const int row = blockIdx.x, tid = threadIdx.x;
  const f32x4 xv = *(const f32x4*)(x + (size_t)row * NDIM + tid * 4);
  float s = xv[0] + xv[1] + xv[2] + xv[3];
  float s2 = xv[0]*xv[0] + xv[1]*xv[1] + xv[2]*xv[2] + xv[3]*xv[3];
  #pragma unroll
  for (int m = 1; m < 64; m <<= 1) { s += __shfl_xor(s, m); s2 += __shfl_xor(s2, m); }
  __shared__ float red[8];
  const int w = tid >> 6, l = tid & 63;
  if (l == 0) { red[w] = s; red[4 + w] = s2; }
  __syncthreads();
  s = red[0] + red[1] + red[2] + red[3];
  s2 = red[4] + red[5] + red[6] + red[7];
  const float mean = s * (1.0f / NDIM);
  const float var = s2 * (1.0f / NDIM) - mean * mean;
  const float rstd = rsqrtf(var + 1e-5f);
  const f32x4 gv = *(const f32x4*)(g + tid * 4);
  const f32x4 bv = *(const f32x4*)(bb + tid * 4);
  s16x4 ov;
  #pragma unroll
  for (int j = 0; j < 4; ++j) ov[j] = f2bf((xv[j] - mean) * rstd * gv[j] + bv[j]);
  *(s16x4*)(out + (size_t)row * NDIM + tid * 4) = ov;
}

// ---------------- Gate: fp32 LN recompute + gate/coef softmax + buckets ----------------
__global__ __launch_bounds__(256)
void gate_k(const float* __restrict__ x1, const float* __restrict__ g,
            const float* __restrict__ bb, const float* __restrict__ gw,
            const float* __restrict__ cw, const float* __restrict__ cb,
            int* __restrict__ counts, int* __restrict__ bucket,
            float* __restrict__ gs, float* __restrict__ c1o)
{
  const int tid = threadIdx.x, l = tid & 63, w = tid >> 6;
  const int t = blockIdx.x * 4 + w;
  f32x4 xv[4];
  #pragma unroll
  for (int it = 0; it < 4; ++it)
    xv[it] = *(const f32x4*)(x1 + (size_t)t * NDIM + it * 256 + l * 4);
  float s = 0.f, s2 = 0.f;
  #pragma unroll
  for (int it = 0; it < 4; ++it)
    #pragma unroll
    for (int j = 0; j < 4; ++j) { s += xv[it][j]; s2 += xv[it][j] * xv[it][j]; }
  #pragma unroll
  for (int m = 1; m < 64; m <<= 1) { s += __shfl_xor(s, m); s2 += __shfl_xor(s2, m); }
  const float mean = s * (1.0f / NDIM);
  const float rstd = rsqrtf(s2 * (1.0f / NDIM) - mean * mean + 1e-5f);
  float acc[10];
  #pragma unroll
  for (int j = 0; j < 10; ++j) acc[j] = 0.f;
  #pragma unroll
  for (int it = 0; it < 4; ++it) {
    #pragma unroll
    for (int j = 0; j < 4; ++j) {
      const int d0 = it * 256 + l * 4 + j;
      const float xn = (xv[it][j] - mean) * rstd * g[d0] + bb[d0];
      const f32x4 g0 = *(const f32x4*)(gw + (size_t)d0 * 8);
      const f32x4 g1 = *(const f32x4*)(gw + (size_t)d0 * 8 + 4);
      #pragma unroll
      for (int q = 0; q < 4; ++q) { acc[q] += xn * g0[q]; acc[4 + q] += xn * g1[q]; }
      acc[8] += xn * cw[d0 * 2]; acc[9] += xn * cw[d0 * 2 + 1];
    }
  }
  #pragma unroll
  for (int j = 0; j < 10; ++j)
    #pragma unroll
    for (int m = 1; m < 64; m <<= 1) acc[j] += __shfl_xor(acc[j], m);
  if (l == 0) {
    int best = 0; float mx = acc[0];
    #pragma unroll
    for (int e = 1; e < 8; ++e) if (acc[e] > mx) { mx = acc[e]; best = e; }
    float se = 0.f;
    #pragma unroll
    for (int e = 0; e < 8; ++e) se += __expf(acc[e] - mx);
    const float gate_val = 1.0f / se;
    const float l0 = acc[8] + cb[0], l1 = acc[9] + cb[1];
    const float cmx = fmaxf(l0, l1);
    const float e0 = __expf(l0 - cmx), e1 = __expf(l1 - cmx);
    const float inv = 1.0f / (e0 + e1);
    const int pos = atomicAdd(&counts[best], 1);
    bucket[best * TOK + pos] = t;
    gs[t] = gate_val * e0 * inv;
    c1o[t] = e1 * inv;
  }
}

// ---- bf16 MFMA GEMM body, m97 structure: 128x128 tile, BK=64, single-buffer ----
// MODE 0: dense, store bf16 (QKV)
// MODE 1: dense split-K, atomic x1 = x + acc + bias (Wo)
// MODE 2: 9-expert up-proj (e<8 gather->he, e==8 identity->hr), GELU bf16
// MODE 3: 9-expert down-proj split-K, atomic out += (acc+bias)*scale (+x1 on e==8,z==0)
struct GemmP {
  const short* A; const short* A2; const short* Bp; const short* Bp2;
  const float* bias; const float* bias2;
  short* outh; short* outh2; float* outf;
  const float* resid; const float* gs; const float* c1;
  const int* bucket; const int* counts;
  int N, K, ktc, nmt;
};

template<int MODE>
__device__ __forceinline__ void gemm_body(const GemmP& p, int bx, int ey, int z,
                                          int tid, char* smem)
{
  char* Al = smem;           // 16KB: [row128][octd8][16B] xor-swizzled
  char* Bl = smem + 16384;   // 16KB: [col128][octd8][16B] xor-swizzled (packed)
  const int l = tid & 63, w = tid >> 6;
  const int wr = w >> 1, wc = w & 1;
  const int ntn = p.N >> 7, nkt = p.K >> 6;
  const int nwg = p.nmt * ntn;
  const int logical = (bx & 7) * (nwg >> 3) + (bx >> 3);
  const int nt = logical / p.nmt;
  const int mt = logical % p.nmt;
  const bool first = (z == 0);
  const int K = p.K, N = p.N;

  int e = 0, cnt = TOK;
  const int* bucket = nullptr;
  if (MODE >= 2) {
    e = ey;
    if (e < 8) {
      cnt = p.counts[e];
      if (mt * 128 >= cnt) return;
      bucket = p.bucket + e * TOK;
    }
  }
  const short* Abase = (MODE == 3 && e == 8) ? p.A2 : p.A;
  const float* bias = (MODE >= 2) ? (e < 8 ? p.bias + (size_t)e * N : p.bias2) : p.bias;
  const short* btile = (MODE >= 2)
      ? (e < 8 ? p.Bp + ((size_t)(e * ntn + nt) * nkt) * 8192
               : p.Bp2 + ((size_t)nt * nkt) * 8192)
      : p.Bp + ((size_t)nt * nkt) * 8192;

  // A staging: chunk c = i*256+tid; row = c>>3, src k-octet = (tid&7)^(row&7)
  const short* aptr[4];
  #pragma unroll
  for (int i = 0; i < 4; ++i) {
    const int rl = (i * 256 + tid) >> 3;
    int row;
    if (bucket) {
      const int bidx = mt * 128 + rl;
      row = bucket[bidx < cnt ? bidx : mt * 128];
    } else row = mt * 128 + rl;
    aptr[i] = Abase + (size_t)row * K + ((tid & 7) ^ (rl & 7)) * 8;
  }

  const int kt0 = z * p.ktc, kt1 = kt0 + p.ktc;

  f32x4 acc[4][4] = {};
  for (int kt = kt0; kt < kt1; ++kt) {
    const short* bsrc = btile + kt * 8192;
    #pragma unroll
    for (int j = 0; j < 4; ++j)
      gload_lds16(bsrc + (j * 256 + tid) * 8, Bl + (j * 256 + (tid & 192)) * 16);
    #pragma unroll
    for (int i = 0; i < 4; ++i)
      gload_lds16(aptr[i] + kt * 64, Al + (i * 256 + (tid & 192)) * 16);
    __syncthreads();
    #pragma unroll
    for (int ks = 0; ks < 2; ++ks) {
      const int octd0 = ks * 4 + (l >> 4);
      s16x8 af[4], bfr[4];
      #pragma unroll
      for (int mf = 0; mf < 4; ++mf) {
        const int r = wr * 64 + mf * 16 + (l & 15);
        af[mf] = *(const s16x8*)(Al + r * 128 + (octd0 ^ (r & 7)) * 16);
      }
      #pragma unroll
      for (int nf = 0; nf < 4; ++nf) {
        const int c2 = wc * 64 + nf * 16 + (l & 15);
        bfr[nf] = *(const s16x8*)(Bl + c2 * 128 + (octd0 ^ (c2 & 7)) * 16);
      }
      #pragma unroll
      for (int mf = 0; mf < 4; ++mf)
        #pragma unroll
        for (int nf = 0; nf < 4; ++nf)
          acc[mf][nf] = __builtin_amdgcn_mfma_f32_16x16x32_bf16(af[mf], bfr[nf], acc[mf][nf], 0, 0, 0);
    }
    __syncthreads();
  }

  short* oh = (MODE == 2) ? (e < 8 ? p.outh : p.outh2) : p.outh;
  #pragma unroll
  for (int mf = 0; mf < 4; ++mf) {
    #pragma unroll
    for (int i = 0; i < 4; ++i) {
      const int rloc = wr * 64 + mf * 16 + (l >> 4) * 4 + i;
      int grow; bool valid = true;
      if (bucket) {
        const int bidx = mt * 128 + rloc;
        valid = bidx < cnt;
        grow = valid ? bucket[bidx] : 0;
      } else grow = mt * 128 + rloc;
      float srow = 1.f;
      if (MODE == 3) srow = (e < 8) ? (valid ? p.gs[grow] : 0.f) : p.c1[grow];
      #pragma unroll
      for (int nf = 0; nf < 4; ++nf) {
        const int col = nt * 128 + wc * 64 + nf * 16 + (l & 15);
        const size_t off = (size_t)grow * N + col;
        const float bc = first ? bias[col] : 0.f;
        if (MODE == 0) {
          oh[off] = f2bf(acc[mf][nf][i] + bc);
        } else if (MODE == 1) {
          atomicAdd(&p.outf[off], acc[mf][nf][i] + bc + (first ? p.resid[off] : 0.f));
        } else if (MODE == 2) {
          const float v = acc[mf][nf][i] + bc;
          const float gv = 0.5f * v * (1.0f + erff(v * 0.70710678f));
          if (valid) oh[off] = f2bf(gv);
        } else if (MODE == 3) {
          if (valid)
            atomicAdd(&p.outf[off], (acc[mf][nf][i] + bc) * srow +
                      ((e == 8 && first) ? p.resid[off] : 0.f));
        }
      }
    }
  }
}

template<int MODE>
__global__ __launch_bounds__(256, 4)
void gemm_k(GemmP p)
{
  __shared__ char smem[32768];
  gemm_body<MODE>(p, blockIdx.x, blockIdx.y, blockIdx.z, threadIdx.x, smem);
}

// ---------------- Flash attention body: 4 waves x 16 q-rows, KV tiles of 64 ----------------
__device__ __forceinline__ void attn_body(const short* __restrict__ qkv,
                                          short* __restrict__ ctx,
                                          int qt, int bh, int tid, char* smem)
{
  char* Klds = smem;            // 8KB
  char* Vlds = smem + 8192;     // 8KB
  char* Plds = smem + 16384;    // 8KB
  const int l = tid & 63, w = tid >> 6;
  const int b = bh >> 4, h = bh & 15;
  const size_t tbase = (size_t)b * 1024;

  const int sq = qt * 64 + w * 16 + (l & 15);
  s16x8 qf[2];
  #pragma unroll
  for (int ks = 0; ks < 2; ++ks)
    qf[ks] = *(const s16x8*)(qkv + (tbase + sq) * 3072 + h * 64 + ks * 32 + (l >> 4) * 8);

  f32x4 o[4] = {};
  float mrow[4], lrow[4];
  #pragma unroll
  for (int i = 0; i < 4; ++i) { mrow[i] = -1e30f; lrow[i] = 0.f; }

  for (int kt = 0; kt < 16; ++kt) {
    #pragma unroll
    for (int i = 0; i < 2; ++i) {
      const int s = i * 256 + tid;
      const int r = s >> 3, c = s & 7, csrc = c ^ (r & 7);
      const short* gsrc = qkv + (tbase + kt * 64 + r) * 3072 + 1024 + h * 64 + csrc * 8;
      gload_lds16(gsrc, Klds + (i * 256 + (tid & 192)) * 16);
    }
    #pragma unroll
    for (int i = 0; i < 2; ++i) {
      const int kv0 = (i * 4 + w) * 8;
      s16x8 vv;
      #pragma unroll
      for (int j = 0; j < 8; ++j)
        vv[j] = qkv[(tbase + kt * 64 + kv0 + j) * 3072 + 2048 + h * 64 + l];
      *(s16x8*)(Vlds + ((l * 128 + kv0 * 2) ^ ((l & 7) << 4))) = vv;
    }
    __syncthreads();

    f32x4 sv[4];
    #pragma unroll
    for (int nf = 0; nf < 4; ++nf) {
      f32x4 a = {0.f, 0.f, 0.f, 0.f};
      const int kv = nf * 16 + (l & 15);
      #pragma unroll
      for (int ks = 0; ks < 2; ++ks) {
        const s16x8 kb = *(const s16x8*)(Klds +
            ((kv * 128 + (ks * 32 + (l >> 4) * 8) * 2) ^ ((kv & 7) << 4)));
        a = __builtin_amdgcn_mfma_f32_16x16x32_bf16(qf[ks], kb, a, 0, 0, 0);
      }
      sv[nf] = a * 0.125f;
    }
    float sc[4], ps[4];
    #pragma unroll
    for (int i = 0; i < 4; ++i) {
      float m = fmaxf(fmaxf(sv[0][i], sv[1][i]), fmaxf(sv[2][i], sv[3][i]));
      #pragma unroll
      for (int msk = 1; msk < 16; msk <<= 1) m = fmaxf(m, __shfl_xor(m, msk));
      const float mn = fmaxf(mrow[i], m);
      sc[i] = __expf(mrow[i] - mn);
      mrow[i] = mn;
      ps[i] = 0.f;
    }
    #pragma unroll
    for (int nf = 0; nf < 4; ++nf)
      #pragma unroll
      for (int i = 0; i < 4; ++i) {
        const float pp = __expf(sv[nf][i] - mrow[i]);
        sv[nf][i] = pp;
        ps[i] += pp;
      }
    #pragma unroll
    for (int i = 0; i < 4; ++i) {
      #pragma unroll
      for (int msk = 1; msk < 16; msk <<= 1) ps[i] += __shfl_xor(ps[i], msk);
      lrow[i] = lrow[i] * sc[i] + ps[i];
    }
    #pragma unroll
    for (int nf = 0; nf < 4; ++nf)
      #pragma unroll
      for (int i = 0; i < 4; ++i) o[nf][i] *= sc[i];

    char* pw = Plds + w * 2048;
    #pragma unroll
    for (int nf = 0; nf < 4; ++nf)
      #pragma unroll
      for (int i = 0; i < 4; ++i) {
        const int q = (l >> 4) * 4 + i;
        *(short*)(pw + ((q * 128 + (nf * 16 + (l & 15)) * 2) ^ ((q & 7) << 4))) = f2bf(sv[nf][i]);
      }
    __syncthreads();
    #pragma unroll
    for (int ks = 0; ks < 2; ++ks) {
      const s16x8 pa = *(const s16x8*)(pw +
          (((l & 15) * 128 + (ks * 32 + (l >> 4) * 8) * 2) ^ ((l & 7) << 4)));
      #pragma unroll
      for (int nf = 0; nf < 4; ++nf) {
        const int dh = nf * 16 + (l & 15);
        const s16x8 vb = *(const s16x8*)(Vlds +
            ((dh * 128 + (ks * 32 + (l >> 4) * 8) * 2) ^ ((dh & 7) << 4)));
        o[nf] = __builtin_amdgcn_mfma_f32_16x16x32_bf16(pa, vb, o[nf], 0, 0, 0);
      }
    }
    __syncthreads();
  }
  #pragma unroll
  for (int i = 0; i < 4; ++i) {
    const float inv = 1.0f / lrow[i];
    const size_t t = tbase + qt * 64 + w * 16 + (l >> 4) * 4 + i;
    #pragma unroll
    for (int nf = 0; nf < 4; ++nf)
      ctx[t * 1024 + h * 64 + nf * 16 + (l & 15)] = f2bf(o[nf][i] * inv);
  }
}

// ---- Fused: QKV GEMM [0,384) + pack Wo [384,448) + pack W1 [448,2496) + pack rW1 [2496,2752) ----
__global__ __launch_bounds__(256, 4)
void qkvpack_k(GemmP g, PackP pWo, PackP pW1, PackP prW1)
{
  __shared__ char smem[34816];
  const int v = blockIdx.x;
  if (v < 384) {
    gemm_body<0>(g, v, 0, 0, threadIdx.x, smem);
  } else if (v < 448) {
    pack_body(pWo, v - 384, 0, threadIdx.x, smem);
  } else if (v < 2496) {
    const int u = v - 448;
    pack_body(pW1, u & 255, u >> 8, threadIdx.x, smem);
  } else {
    pack_body(prW1, v - 2496, 0, threadIdx.x, smem);
  }
}

// ---- Fused: attention [0,512) + pack W2 [512,2560) + pack rW2 [2560,2816) ----
__global__ __launch_bounds__(256, 2)
void attnpack_k(const short* qkv, short* ctx, PackP pW2, PackP prW2)
{
  __shared__ char smem[34816];
  const int v = blockIdx.x;
  if (v < 512) {
    attn_body(qkv, ctx, v & 15, v >> 4, threadIdx.x, smem);
  } else if (v < 2560) {
    const int u = v - 512;
    pack_body(pW2, u & 255, u >> 8, threadIdx.x, smem);
  } else {
    pack_body(prW2, v - 2560, 0, threadIdx.x, smem);
  }
}

extern "C" void kernel_launch(void* const* d_in, const int* in_sizes, int n_in,
                              void* d_out, int out_size, void* d_ws, size_t ws_size,
                              hipStream_t stream)
{
  const float* x    = (const float*)d_in[0];
  const float* ln1g = (const float*)d_in[1];
  const float* ln1b = (const float*)d_in[2];
  const float* Wqkv = (const float*)d_in[3];
  const float* bqkv = (const float*)d_in[4];
  const float* Wo   = (const float*)d_in[5];
  const float* bo   = (const float*)d_in[6];
  const float* ln2g = (const float*)d_in[7];
  const float* ln2b = (const float*)d_in[8];
  const float* gw   = (const float*)d_in[9];
  const float* W1   = (const float*)d_in[10];
  const float* b1   = (const float*)d_in[11];
  const float* W2   = (const float*)d_in[12];
  const float* b2   = (const float*)d_in[13];
  const float* rW1  = (const float*)d_in[14];
  const float* rb1  = (const float*)d_in[15];
  const float* rW2  = (const float*)d_in[16];
  const float* rb2  = (const float*)d_in[17];
  const float* cw   = (const float*)d_in[18];
  const float* cb   = (const float*)d_in[19];
  float* out = (float*)d_out;

  char* ws = (char*)d_ws;
  const size_t MB = 1024 * 1024;
  short* xn1    = (short*)(ws + 0);          // 4 MB
  short* qkv    = (short*)(ws + 4 * MB);     // 12 MB
  short* he     = (short*)(ws + 4 * MB);     // 16 MB (aliases qkv+ctx, dead by then)
  short* ctx    = (short*)(ws + 16 * MB);    // 4 MB
  float* x1     = (float*)(ws + 20 * MB);    // 8 MB
  short* xn2    = (short*)(ws + 28 * MB);    // 4 MB
  short* hr     = (short*)(ws + 32 * MB);    // 16 MB
  int*   counts = (int*)(ws + 56 * MB);
  int*   bucket = (int*)(ws + 56 * MB + 256);
  float* gs     = (float*)(ws + 56 * MB + 256 + 64 * 1024);
  float* c1     = (float*)(ws + 56 * MB + 256 + 64 * 1024 + 8192);
  short* Wqkvp  = (short*)(ws + 64 * MB);    // 6 MB
  short* Wop    = (short*)(ws + 70 * MB);    // 2 MB
  short* W1p    = (short*)(ws + 72 * MB);    // 64 MB
  short* W2p    = (short*)(ws + 136 * MB);   // 64 MB
  short* rW1p   = (short*)(ws + 200 * MB);   // 8 MB
  short* rW2p   = (short*)(ws + 208 * MB);   // 8 MB

  hipMemsetAsync(counts, 0, 8 * sizeof(int), stream);
  hipMemsetAsync(x1, 0, TOK * NDIM * sizeof(float), stream);
  hipMemsetAsync(out, 0, TOK * NDIM * sizeof(float), stream);

  // pack Wqkv only (needed by the fused QKV kernel)
  PackP pk{Wqkv, Wqkvp, 1024, 3072, 16};
  pack_k<<<dim3(12 * 16, 1), 256, 0, stream>>>(pk);

  ln_k<<<TOK, 256, 0, stream>>>(x, ln1g, ln1b, xn1);

  // fused: QKV GEMM + pack {Wo, W1, rW1}
  GemmP p{};
  p.A = xn1; p.Bp = Wqkvp; p.bias = bqkv; p.outh = qkv;
  p.N = 3072; p.K = 1024; p.ktc = 16; p.nmt = 16;
  PackP pWo{Wo, Wop, 1024, 1024, 16};
  PackP pW1{W1, W1p, 1024, 4096, 16};
  PackP prW1{rW1, rW1p, 1024, 4096, 16};
  qkvpack_k<<<dim3(2752), 256, 0, stream>>>(p, pWo, pW1, prW1);

  // fused: attention + pack {W2, rW2}
  PackP pW2{W2, W2p, 4096, 1024, 64};
  PackP prW2{rW2, rW2p, 4096, 1024, 64};
  attnpack_k<<<dim3(2816), 256, 0, stream>>>(qkv, ctx, pW2, prW2);

  // x1 = x + ctx @ Wo + bo  (nwg = 128, split-K = 2)
  p = GemmP{};
  p.A = ctx; p.Bp = Wop; p.bias = bo; p.outf = x1; p.resid = x;
  p.N = 1024; p.K = 1024; p.ktc = 8; p.nmt = 16;
  gemm_k<1><<<dim3(128, 1, 2), 256, 0, stream>>>(p);

  ln_k<<<TOK, 256, 0, stream>>>(x1, ln2g, ln2b, xn2);
  gate_k<<<TOK / 4, 256, 0, stream>>>(x1, ln2g, ln2b, gw, cw, cb, counts, bucket, gs, c1);

  // fused up-proj (nwg = 16*32 = 512): e<8 he = gelu(gather(xn2)@W1+b1); e==8 hr = gelu(xn2@rW1+rb1)
  p = GemmP{};
  p.A = xn2; p.Bp = W1p; p.Bp2 = rW1p; p.bias = b1; p.bias2 = rb1;
  p.outh = he; p.outh2 = hr; p.N = 4096; p.K = 1024; p.ktc = 16; p.nmt = 16;
  p.bucket = bucket; p.counts = counts;
  gemm_k<2><<<dim3(512, 9), 256, 0, stream>>>(p);

  // fused down-proj (nwg = 128, split-K = 2): out += (he@W2+b2)*gs | (hr@rW2+rb2)*c1 + x1
  p = GemmP{};
  p.A = he; p.A2 = hr; p.Bp = W2p; p.Bp2 = rW2p; p.bias = b2; p.bias2 = rb2;
  p.outf = out; p.resid = x1; p.gs = gs; p.c1 = c1;
  p.N = 1024; p.K = 4096; p.ktc = 32; p.nmt = 16;
  p.bucket = bucket; p.counts = counts;
  gemm_k<3><<<dim3(128, 9, 2), 256, 0, stream>>>(p);
}